// Round 1
// baseline (785.704 us; speedup 1.0000x reference)
//
#include <hip/hip_runtime.h>
#include <hip/hip_bf16.h>

typedef __attribute__((ext_vector_type(4))) float f32x4;
typedef __attribute__((ext_vector_type(8))) short bf16x8;
typedef __attribute__((ext_vector_type(4))) unsigned short u16x4;
typedef unsigned short u16;

constexpr int HH = 384, WW = 384;
constexpr int AWP = 386;               // padded activation width (+1 halo each side)
constexpr int ASTR = AWP * 64;         // elements per padded activation row
constexpr int NPIX = HH * WW;          // 147456
constexpr int NPIX3 = NPIX * 3;        // 442368 (one output tensor)
constexpr int DP = 398, DPLANE = DP * DP;  // data padded by 7 each side
constexpr size_t ACT_BYTES = (size_t)AWP * AWP * 64 * 2;  // 19,071,488

__device__ __forceinline__ u16 f2bf(float f) {
  union { __hip_bfloat16 h; u16 u; } v; v.h = __float2bfloat16(f); return v.u;
}
__device__ __forceinline__ float bf2f(u16 u) {
  union { float f; unsigned int i; } v; v.i = ((unsigned int)u) << 16; return v.f;
}

// ---------------- weight/bias repack ----------------
// wpack[c][oc][k] bf16, k = tap*64 + ic (tap-major so 8 consecutive k = 8 consecutive ic)
// bpack[c][oc] f32 (oc>=35 zeroed for conv 6); wfr[ictap][oc] f32 for first conv
__global__ void repack_kern(const float* __restrict__ w1, const float* __restrict__ w2,
                            const float* __restrict__ wo, const float* __restrict__ b1,
                            const float* __restrict__ b2, const float* __restrict__ bo,
                            const float* __restrict__ wf,
                            u16* __restrict__ wpack, float* __restrict__ bpack,
                            float* __restrict__ wfr)
{
  const int idx = blockIdx.x * 256 + threadIdx.x;
  constexpr int NW = 7 * 64 * 576;
  if (idx < NW) {
    const int c = idx / (64 * 576);
    const int r = idx % (64 * 576);
    const int oc = r / 576, k = r % 576;
    const int tap = k >> 6, ic = k & 63;
    float v;
    if (c < 6) {
      const float* s = (c & 1) ? w2 : w1;
      v = s[(((c >> 1) * 64 + oc) * 64 + ic) * 9 + tap];
    } else {
      v = (oc < 35) ? wo[(oc * 64 + ic) * 9 + tap] : 0.f;
    }
    wpack[idx] = f2bf(v);
  } else if (idx < NW + 448) {
    const int t = idx - NW;
    const int c = t / 64, oc = t % 64;
    float v;
    if (c < 6) v = ((c & 1) ? b2 : b1)[(c >> 1) * 64 + oc];
    else v = (oc < 35) ? bo[oc] : 0.f;
    bpack[t] = v;
  } else if (idx < NW + 448 + 3456) {
    const int t = idx - NW - 448;
    const int ictap = t / 64, oc = t % 64;
    wfr[t] = wf[oc * 54 + ictap];
  }
}

// ---------------- pad-copy data (fp32, halo 7) ----------------
__global__ void padcopy_kern(const float* __restrict__ data, float* __restrict__ dpad)
{
  const int idx = blockIdx.x * 256 + threadIdx.x;  // exactly 442368 threads
  const int c = idx / NPIX, r = idx % NPIX;
  const int y = r / WW, x = r % WW;
  dpad[c * DPLANE + (y + 7) * DP + (x + 7)] = data[idx];
}

// ---------------- first conv: 6 -> 64, fp32 direct, writes NHWC bf16 ----------------
__global__ __launch_bounds__(256)
void conv1_kern(const float* __restrict__ din, const float* __restrict__ wr,
                const float* __restrict__ bias, u16* __restrict__ outb)
{
  const int px = blockIdx.x * 256 + threadIdx.x;  // 576*256 = NPIX exactly
  const int y = px / WW, x = px % WW;
  f32x4 acc[16];
  #pragma unroll
  for (int j = 0; j < 16; ++j) acc[j] = *(const f32x4*)(bias + j * 4);
  for (int ic = 0; ic < 6; ++ic) {
    #pragma unroll
    for (int kr = 0; kr < 3; ++kr) {
      const int yy = y + kr - 1;
      #pragma unroll
      for (int kc = 0; kc < 3; ++kc) {
        const int xx = x + kc - 1;
        float v = 0.f;
        if (yy >= 0 && yy < HH && xx >= 0 && xx < WW)
          v = din[ic * NPIX + yy * WW + xx];
        const float* w = wr + ((ic * 3 + kr) * 3 + kc) * 64;
        #pragma unroll
        for (int j = 0; j < 16; ++j) {
          const f32x4 wv = *(const f32x4*)(w + j * 4);
          acc[j] += wv * v;
        }
      }
    }
  }
  u16* ob = outb + ((size_t)(y + 1) * AWP + (x + 1)) * 64;
  #pragma unroll
  for (int j = 0; j < 16; ++j) {
    u16x4 s;
    #pragma unroll
    for (int t = 0; t < 4; ++t) s[t] = f2bf(acc[j][t]);
    *(u16x4*)(ob + j * 4) = s;
  }
}

// ---------------- MFMA implicit-GEMM 3x3 conv, 64->64 (or ->35 padded) ----------------
// MODE 0: +bias, relu, store bf16 NHWC padded
// MODE 1: +bias, +residual (in-place on outb), store bf16 NHWC padded
// MODE 2: +bias, store f32 [pix][64]
template<int MODE>
__global__ __launch_bounds__(128)
void conv_mfma(const u16* __restrict__ in, const u16* __restrict__ wp,
               const float* __restrict__ bias, u16* __restrict__ outb,
               float* __restrict__ outf)
{
  const int lane = threadIdx.x & 63;
  const int wv = threadIdx.x >> 6;
  const int l15 = lane & 15, g8 = lane >> 4;
  const int y = blockIdx.y;
  const int x0 = blockIdx.x * 128 + wv * 64;

  f32x4 acc[4][4];
  #pragma unroll
  for (int m = 0; m < 4; ++m)
    #pragma unroll
    for (int n = 0; n < 4; ++n)
      acc[m][n] = f32x4{0.f, 0.f, 0.f, 0.f};

  #pragma unroll
  for (int kr = 0; kr < 3; ++kr) {
    const u16* inr = in + (size_t)(y + kr) * ASTR;   // padded row (y-1+kr)+1
    #pragma unroll
    for (int kc = 0; kc < 3; ++kc) {
      #pragma unroll
      for (int ich = 0; ich < 2; ++ich) {
        const int kb = (kr * 3 + kc) * 64 + ich * 32;
        bf16x8 a[4], b[4];
        #pragma unroll
        for (int m = 0; m < 4; ++m)
          a[m] = *(const bf16x8*)(wp + (m * 16 + l15) * 576 + kb + g8 * 8);
        #pragma unroll
        for (int n = 0; n < 4; ++n)
          b[n] = *(const bf16x8*)(inr + (size_t)(x0 + n * 16 + l15 + kc) * 64 + ich * 32 + g8 * 8);
        #pragma unroll
        for (int m = 0; m < 4; ++m)
          #pragma unroll
          for (int n = 0; n < 4; ++n)
            acc[m][n] = __builtin_amdgcn_mfma_f32_16x16x32_bf16(a[m], b[n], acc[m][n], 0, 0, 0);
      }
    }
  }

  const int oc_lo = g8 * 4;
  #pragma unroll
  for (int m = 0; m < 4; ++m) {
    const int oc0 = m * 16 + oc_lo;                  // D row = (lane>>4)*4 + reg
    const f32x4 bv = *(const f32x4*)(bias + oc0);
    #pragma unroll
    for (int n = 0; n < 4; ++n) {
      const int px = x0 + n * 16 + l15;              // D col = lane&15
      f32x4 v = acc[m][n] + bv;
      if constexpr (MODE == 0) {
        #pragma unroll
        for (int j = 0; j < 4; ++j) v[j] = v[j] > 0.f ? v[j] : 0.f;
      }
      if constexpr (MODE == 1) {
        const u16x4 r = *(const u16x4*)(outb + ((size_t)(y + 1) * AWP + (px + 1)) * 64 + oc0);
        #pragma unroll
        for (int j = 0; j < 4; ++j) v[j] += bf2f(r[j]);
      }
      if constexpr (MODE <= 1) {
        u16x4 s;
        #pragma unroll
        for (int j = 0; j < 4; ++j) s[j] = f2bf(v[j]);
        *(u16x4*)(outb + ((size_t)(y + 1) * AWP + (px + 1)) * 64 + oc0) = s;
      } else {
        *(f32x4*)(outf + ((size_t)y * WW + px) * 64 + oc0) = v;
      }
    }
  }
}

// ---------------- KPN apply: radial softmax + gather ----------------
template<int WIDE>
__device__ __forceinline__ void kpn_w(const float* __restrict__ ckp,
                                      const float* __restrict__ base,
                                      float* __restrict__ o)
{
  float ck[WIDE];
  #pragma unroll
  for (int i = 0; i < WIDE; ++i) ck[i] = fabsf(ckp[i]);
  float s = 0.f, p0 = 0.f, p1 = 0.f, p2 = 0.f;
  #pragma unroll
  for (int a = 0; a < WIDE; ++a) {
    #pragma unroll
    for (int b = 0; b < WIDE; ++b) {
      const int d2 = a * a + b * b;
      int li = 0;                                     // integer floor sqrt, folds
      while ((li + 1) * (li + 1) <= d2) ++li;
      const bool exact = (li * li == d2);
      const int hraw = li + (exact ? 0 : 1);
      const int lidx = li < WIDE - 1 ? li : WIDE - 1;
      const int hidx = hraw < WIDE - 1 ? hraw : WIDE - 1;
      const bool msk = d2 <= (WIDE - 1) * (WIDE - 1);
      float e;
      if (msk) {
        const float d = sqrtf((float)d2);
        const float wlo = exact ? 1.f : ((float)hraw - d);
        const float whi = exact ? 0.f : (d - (float)li);
        const float q = wlo * ck[lidx] + whi * ck[hidx];
        e = __expf(q);
      } else {
        e = 1.f;                                      // masked: logit 0, still in softmax
      }
      const float mult = (float)(((a > 0) ? 2 : 1) * ((b > 0) ? 2 : 1));
      s += mult * e;
      #pragma unroll
      for (int c = 0; c < 3; ++c) {
        const float* bc = base + c * DPLANE;
        float g = bc[a * DP + b];
        if (b > 0) g += bc[a * DP - b];
        if (a > 0) g += bc[-a * DP + b];
        if (a > 0 && b > 0) g += bc[-a * DP - b];
        if (c == 0) p0 += e * g; else if (c == 1) p1 += e * g; else p2 += e * g;
      }
    }
  }
  const float inv = 1.f / s;
  o[0] = p0 * inv; o[NPIX] = p1 * inv; o[2 * NPIX] = p2 * inv;
}

__global__ __launch_bounds__(256)
void kpn_kern(const float* __restrict__ core, const float* __restrict__ dpad,
              float* __restrict__ out)
{
  const int px = blockIdx.x * 256 + threadIdx.x;      // 576*256 = NPIX exactly
  const int y = px / WW, x = px % WW;
  const float* base = dpad + (size_t)(y + 7) * DP + (x + 7);
  const float* ck = core + (size_t)px * 64;
  float* o = out + NPIX3 + px;
  kpn_w<2>(ck + 0,  base, o);
  kpn_w<3>(ck + 2,  base, o + (size_t)NPIX3);
  kpn_w<4>(ck + 5,  base, o + (size_t)2 * NPIX3);
  kpn_w<5>(ck + 9,  base, o + (size_t)3 * NPIX3);
  kpn_w<6>(ck + 14, base, o + (size_t)4 * NPIX3);
  kpn_w<7>(ck + 20, base, o + (size_t)5 * NPIX3);
  kpn_w<8>(ck + 27, base, o + (size_t)6 * NPIX3);
}

// ---------------- launch ----------------
extern "C" void kernel_launch(void* const* d_in, const int* in_sizes, int n_in,
                              void* d_out, int out_size, void* d_ws, size_t ws_size,
                              hipStream_t stream)
{
  const float* d_est   = (const float*)d_in[0];
  const float* data    = (const float*)d_in[1];
  const float* w_first = (const float*)d_in[2];
  const float* b_first = (const float*)d_in[3];
  const float* w_blk1  = (const float*)d_in[4];
  const float* b_blk1  = (const float*)d_in[5];
  const float* w_blk2  = (const float*)d_in[6];
  const float* b_blk2  = (const float*)d_in[7];
  const float* w_out   = (const float*)d_in[8];
  const float* b_out   = (const float*)d_in[9];

  char* ws = (char*)d_ws;
  const size_t OFF_A1    = ACT_BYTES;
  const size_t OFF_CORE  = 2 * ACT_BYTES;
  const size_t OFF_DPAD  = OFF_CORE + (size_t)NPIX * 64 * 4;
  const size_t OFF_WPACK = OFF_DPAD + (size_t)3 * DPLANE * 4;
  const size_t OFF_BPACK = OFF_WPACK + (size_t)7 * 64 * 576 * 2;
  const size_t OFF_WFR   = OFF_BPACK + 448 * 4;

  u16*   A0    = (u16*)(ws);
  u16*   A1    = (u16*)(ws + OFF_A1);
  float* core  = (float*)(ws + OFF_CORE);
  float* dpad  = (float*)(ws + OFF_DPAD);
  u16*   wpack = (u16*)(ws + OFF_WPACK);
  float* bpack = (float*)(ws + OFF_BPACK);
  float* wfr   = (float*)(ws + OFF_WFR);

  hipMemsetAsync(A0, 0, ACT_BYTES, stream);
  hipMemsetAsync(A1, 0, ACT_BYTES, stream);
  hipMemsetAsync(dpad, 0, (size_t)3 * DPLANE * 4, stream);
  // output 0 is an exact copy of `data`
  hipMemcpyAsync(d_out, data, (size_t)NPIX3 * 4, hipMemcpyDeviceToDevice, stream);

  repack_kern<<<1024, 256, 0, stream>>>(w_blk1, w_blk2, w_out, b_blk1, b_blk2, b_out,
                                        w_first, wpack, bpack, wfr);
  padcopy_kern<<<1728, 256, 0, stream>>>(data, dpad);
  conv1_kern<<<576, 256, 0, stream>>>(d_est, wfr, b_first, A0);

  dim3 cg(3, 384);
  for (int i = 0; i < 3; ++i) {
    conv_mfma<0><<<cg, 128, 0, stream>>>(A0, wpack + (size_t)(2 * i) * 64 * 576,
                                         bpack + (2 * i) * 64, A1, nullptr);
    conv_mfma<1><<<cg, 128, 0, stream>>>(A1, wpack + (size_t)(2 * i + 1) * 64 * 576,
                                         bpack + (2 * i + 1) * 64, A0, nullptr);
  }
  conv_mfma<2><<<cg, 128, 0, stream>>>(A0, wpack + (size_t)6 * 64 * 576,
                                       bpack + 6 * 64, nullptr, core);
  kpn_kern<<<576, 256, 0, stream>>>(core, dpad, (float*)d_out);
}

// Round 3
// 538.575 us; speedup vs baseline: 1.4589x; 1.4589x over previous
//
#include <hip/hip_runtime.h>
#include <hip/hip_bf16.h>

typedef __attribute__((ext_vector_type(4))) float f32x4;
typedef __attribute__((ext_vector_type(8))) short bf16x8;
typedef __attribute__((ext_vector_type(4))) unsigned short u16x4;
typedef unsigned short u16;

constexpr int HH = 384, WW = 384;
constexpr int AWP = 386;               // padded activation width (+1 halo each side)
constexpr int ASTR = AWP * 64;         // elements per padded activation row
constexpr int NPIX = HH * WW;          // 147456
constexpr int NPIX3 = NPIX * 3;        // 442368 (one output tensor)
constexpr int DP = 398, DPLANE = DP * DP;  // data padded by 7 each side
constexpr size_t ACT_BYTES = (size_t)AWP * AWP * 64 * 2;  // 19,071,488

__device__ __forceinline__ u16 f2bf(float f) {
  union { __hip_bfloat16 h; u16 u; } v; v.h = __float2bfloat16(f); return v.u;
}
__device__ __forceinline__ float bf2f(u16 u) {
  union { float f; unsigned int i; } v; v.i = ((unsigned int)u) << 16; return v.f;
}

// ---------------- weight/bias repack ----------------
// wpack[c][oc][k] bf16, k = tap*64 + ic (tap-major so 8 consecutive k = 8 consecutive ic)
// bpack[c][oc] f32 (oc>=35 zeroed for conv 6); wfr[ictap][oc] f32 for first conv
__global__ void repack_kern(const float* __restrict__ w1, const float* __restrict__ w2,
                            const float* __restrict__ wo, const float* __restrict__ b1,
                            const float* __restrict__ b2, const float* __restrict__ bo,
                            const float* __restrict__ wf,
                            u16* __restrict__ wpack, float* __restrict__ bpack,
                            float* __restrict__ wfr)
{
  const int idx = blockIdx.x * 256 + threadIdx.x;
  constexpr int NW = 7 * 64 * 576;
  if (idx < NW) {
    const int c = idx / (64 * 576);
    const int r = idx % (64 * 576);
    const int oc = r / 576, k = r % 576;
    const int tap = k >> 6, ic = k & 63;
    float v;
    if (c < 6) {
      const float* s = (c & 1) ? w2 : w1;
      v = s[(((c >> 1) * 64 + oc) * 64 + ic) * 9 + tap];
    } else {
      v = (oc < 35) ? wo[(oc * 64 + ic) * 9 + tap] : 0.f;
    }
    wpack[idx] = f2bf(v);
  } else if (idx < NW + 448) {
    const int t = idx - NW;
    const int c = t / 64, oc = t % 64;
    float v;
    if (c < 6) v = ((c & 1) ? b2 : b1)[(c >> 1) * 64 + oc];
    else v = (oc < 35) ? bo[oc] : 0.f;
    bpack[t] = v;
  } else if (idx < NW + 448 + 3456) {
    const int t = idx - NW - 448;
    const int ictap = t / 64, oc = t % 64;
    wfr[t] = wf[oc * 54 + ictap];
  }
}

// ---------------- pad-copy data (fp32, halo 7) ----------------
__global__ void padcopy_kern(const float* __restrict__ data, float* __restrict__ dpad)
{
  const int idx = blockIdx.x * 256 + threadIdx.x;  // exactly 442368 threads
  const int c = idx / NPIX, r = idx % NPIX;
  const int y = r / WW, x = r % WW;
  dpad[c * DPLANE + (y + 7) * DP + (x + 7)] = data[idx];
}

// ---------------- first conv: 6 -> 64, fp32 direct, writes NHWC bf16 ----------------
__global__ __launch_bounds__(256)
void conv1_kern(const float* __restrict__ din, const float* __restrict__ wr,
                const float* __restrict__ bias, u16* __restrict__ outb)
{
  const int px = blockIdx.x * 256 + threadIdx.x;  // 576*256 = NPIX exactly
  const int y = px / WW, x = px % WW;
  f32x4 acc[16];
  #pragma unroll
  for (int j = 0; j < 16; ++j) acc[j] = *(const f32x4*)(bias + j * 4);
  for (int ic = 0; ic < 6; ++ic) {
    #pragma unroll
    for (int kr = 0; kr < 3; ++kr) {
      const int yy = y + kr - 1;
      #pragma unroll
      for (int kc = 0; kc < 3; ++kc) {
        const int xx = x + kc - 1;
        float v = 0.f;
        if (yy >= 0 && yy < HH && xx >= 0 && xx < WW)
          v = din[ic * NPIX + yy * WW + xx];
        const float* w = wr + ((ic * 3 + kr) * 3 + kc) * 64;
        #pragma unroll
        for (int j = 0; j < 16; ++j) {
          const f32x4 wv = *(const f32x4*)(w + j * 4);
          acc[j] += wv * v;
        }
      }
    }
  }
  u16* ob = outb + ((size_t)(y + 1) * AWP + (x + 1)) * 64;
  #pragma unroll
  for (int j = 0; j < 16; ++j) {
    u16x4 s;
    #pragma unroll
    for (int t = 0; t < 4; ++t) s[t] = f2bf(acc[j][t]);
    *(u16x4*)(ob + j * 4) = s;
  }
}

// ---------------- MFMA implicit-GEMM 3x3 conv, 64->64 (or ->35 planar f32) ----------------
// MODE 0: +bias, relu, store bf16 NHWC padded
// MODE 1: +bias, +residual (in-place on outb), store bf16 NHWC padded
// MODE 2: +bias, store f32 planar [oc][pix] for oc < 35
template<int MODE>
__global__ __launch_bounds__(128)
void conv_mfma(const u16* __restrict__ in, const u16* __restrict__ wp,
               const float* __restrict__ bias, u16* __restrict__ outb,
               float* __restrict__ outf)
{
  const int lane = threadIdx.x & 63;
  const int wv = threadIdx.x >> 6;
  const int l15 = lane & 15, g8 = lane >> 4;
  const int y = blockIdx.y;
  const int x0 = blockIdx.x * 128 + wv * 64;

  f32x4 acc[4][4];
  #pragma unroll
  for (int m = 0; m < 4; ++m)
    #pragma unroll
    for (int n = 0; n < 4; ++n)
      acc[m][n] = f32x4{0.f, 0.f, 0.f, 0.f};

  #pragma unroll
  for (int kr = 0; kr < 3; ++kr) {
    const u16* inr = in + (size_t)(y + kr) * ASTR;   // padded row (y-1+kr)+1
    #pragma unroll
    for (int kc = 0; kc < 3; ++kc) {
      #pragma unroll
      for (int ich = 0; ich < 2; ++ich) {
        const int kb = (kr * 3 + kc) * 64 + ich * 32;
        bf16x8 a[4], b[4];
        #pragma unroll
        for (int m = 0; m < 4; ++m)
          a[m] = *(const bf16x8*)(wp + (m * 16 + l15) * 576 + kb + g8 * 8);
        #pragma unroll
        for (int n = 0; n < 4; ++n)
          b[n] = *(const bf16x8*)(inr + (size_t)(x0 + n * 16 + l15 + kc) * 64 + ich * 32 + g8 * 8);
        #pragma unroll
        for (int m = 0; m < 4; ++m)
          #pragma unroll
          for (int n = 0; n < 4; ++n)
            acc[m][n] = __builtin_amdgcn_mfma_f32_16x16x32_bf16(a[m], b[n], acc[m][n], 0, 0, 0);
      }
    }
  }

  const int oc_lo = g8 * 4;
  #pragma unroll
  for (int m = 0; m < 4; ++m) {
    const int oc0 = m * 16 + oc_lo;                  // D row = (lane>>4)*4 + reg
    const f32x4 bv = *(const f32x4*)(bias + oc0);
    #pragma unroll
    for (int n = 0; n < 4; ++n) {
      const int px = x0 + n * 16 + l15;              // D col = lane&15
      f32x4 v = acc[m][n] + bv;
      if constexpr (MODE == 0) {
        #pragma unroll
        for (int j = 0; j < 4; ++j) v[j] = v[j] > 0.f ? v[j] : 0.f;
      }
      if constexpr (MODE == 1) {
        const u16x4 r = *(const u16x4*)(outb + ((size_t)(y + 1) * AWP + (px + 1)) * 64 + oc0);
        #pragma unroll
        for (int j = 0; j < 4; ++j) v[j] += bf2f(r[j]);
      }
      if constexpr (MODE <= 1) {
        u16x4 s;
        #pragma unroll
        for (int j = 0; j < 4; ++j) s[j] = f2bf(v[j]);
        *(u16x4*)(outb + ((size_t)(y + 1) * AWP + (px + 1)) * 64 + oc0) = s;
      } else {
        // planar f32 store, only real channels
        #pragma unroll
        for (int j = 0; j < 4; ++j) {
          const int oc = oc0 + j;
          if (oc < 35) outf[(size_t)oc * NPIX + (size_t)y * WW + px] = v[j];
        }
      }
    }
  }
}

// ---------------- KPN apply: one kernel per section (low reg pressure) ----------------
template<int WIDE, int OFF, int SEC>
__global__ __launch_bounds__(256, 4)
void kpn_sec(const float* __restrict__ corep, const float* __restrict__ dpad,
             float* __restrict__ out)
{
  const int px = blockIdx.x * 256 + threadIdx.x;      // 576*256 = NPIX exactly
  const int y = px / WW, x = px % WW;
  const float* base = dpad + (size_t)(y + 7) * DP + (x + 7);

  float ck[WIDE];
  #pragma unroll
  for (int i = 0; i < WIDE; ++i) ck[i] = fabsf(corep[(size_t)(OFF + i) * NPIX + px]);

  float s = 0.f, p0 = 0.f, p1 = 0.f, p2 = 0.f;
  #pragma unroll
  for (int a = 0; a < WIDE; ++a) {
    #pragma unroll
    for (int b = 0; b < WIDE; ++b) {
      const int d2 = a * a + b * b;
      int li = 0;                                     // integer floor sqrt, folds
      while ((li + 1) * (li + 1) <= d2) ++li;
      const bool exact = (li * li == d2);
      const int hraw = li + (exact ? 0 : 1);
      const int lidx = li < WIDE - 1 ? li : WIDE - 1;
      const int hidx = hraw < WIDE - 1 ? hraw : WIDE - 1;
      const bool msk = d2 <= (WIDE - 1) * (WIDE - 1);
      float e;
      if (msk) {
        const float d = sqrtf((float)d2);
        const float wlo = exact ? 1.f : ((float)hraw - d);
        const float whi = exact ? 0.f : (d - (float)li);
        const float q = wlo * ck[lidx] + whi * ck[hidx];
        e = __expf(q);
      } else {
        e = 1.f;                                      // masked: logit 0, still in softmax
      }
      const float mult = (float)(((a > 0) ? 2 : 1) * ((b > 0) ? 2 : 1));
      s += mult * e;
      #pragma unroll
      for (int c = 0; c < 3; ++c) {
        const float* bc = base + c * DPLANE;
        float g = bc[a * DP + b];
        if (b > 0) g += bc[a * DP - b];
        if (a > 0) g += bc[-a * DP + b];
        if (a > 0 && b > 0) g += bc[-a * DP - b];
        if (c == 0) p0 += e * g; else if (c == 1) p1 += e * g; else p2 += e * g;
      }
    }
  }
  const float inv = 1.f / s;
  float* o = out + (size_t)(SEC + 1) * NPIX3 + px;
  o[0] = p0 * inv; o[NPIX] = p1 * inv; o[2 * NPIX] = p2 * inv;
}

// ---------------- launch ----------------
extern "C" void kernel_launch(void* const* d_in, const int* in_sizes, int n_in,
                              void* d_out, int out_size, void* d_ws, size_t ws_size,
                              hipStream_t stream)
{
  const float* d_est   = (const float*)d_in[0];
  const float* data    = (const float*)d_in[1];
  const float* w_first = (const float*)d_in[2];
  const float* b_first = (const float*)d_in[3];
  const float* w_blk1  = (const float*)d_in[4];
  const float* b_blk1  = (const float*)d_in[5];
  const float* w_blk2  = (const float*)d_in[6];
  const float* b_blk2  = (const float*)d_in[7];
  const float* w_out   = (const float*)d_in[8];
  const float* b_out   = (const float*)d_in[9];

  char* ws = (char*)d_ws;
  const size_t OFF_A1    = ACT_BYTES;
  const size_t OFF_CORE  = 2 * ACT_BYTES;
  const size_t OFF_DPAD  = OFF_CORE + (size_t)35 * NPIX * 4;
  const size_t OFF_WPACK = OFF_DPAD + (size_t)3 * DPLANE * 4;
  const size_t OFF_BPACK = OFF_WPACK + (size_t)7 * 64 * 576 * 2;
  const size_t OFF_WFR   = OFF_BPACK + 448 * 4;

  u16*   A0    = (u16*)(ws);
  u16*   A1    = (u16*)(ws + OFF_A1);
  float* corep = (float*)(ws + OFF_CORE);
  float* dpad  = (float*)(ws + OFF_DPAD);
  u16*   wpack = (u16*)(ws + OFF_WPACK);
  float* bpack = (float*)(ws + OFF_BPACK);
  float* wfr   = (float*)(ws + OFF_WFR);

  hipMemsetAsync(A0, 0, ACT_BYTES, stream);
  hipMemsetAsync(A1, 0, ACT_BYTES, stream);
  hipMemsetAsync(dpad, 0, (size_t)3 * DPLANE * 4, stream);
  // output 0 is an exact copy of `data`
  hipMemcpyAsync(d_out, data, (size_t)NPIX3 * 4, hipMemcpyDeviceToDevice, stream);

  repack_kern<<<1024, 256, 0, stream>>>(w_blk1, w_blk2, w_out, b_blk1, b_blk2, b_out,
                                        w_first, wpack, bpack, wfr);
  padcopy_kern<<<1728, 256, 0, stream>>>(data, dpad);
  conv1_kern<<<576, 256, 0, stream>>>(d_est, wfr, b_first, A0);

  dim3 cg(3, 384);
  for (int i = 0; i < 3; ++i) {
    conv_mfma<0><<<cg, 128, 0, stream>>>(A0, wpack + (size_t)(2 * i) * 64 * 576,
                                         bpack + (2 * i) * 64, A1, nullptr);
    conv_mfma<1><<<cg, 128, 0, stream>>>(A1, wpack + (size_t)(2 * i + 1) * 64 * 576,
                                         bpack + (2 * i + 1) * 64, A0, nullptr);
  }
  conv_mfma<2><<<cg, 128, 0, stream>>>(A0, wpack + (size_t)6 * 64 * 576,
                                       bpack + 6 * 64, nullptr, corep);

  float* out = (float*)d_out;
  kpn_sec<2, 0, 0><<<576, 256, 0, stream>>>(corep, dpad, out);
  kpn_sec<3, 2, 1><<<576, 256, 0, stream>>>(corep, dpad, out);
  kpn_sec<4, 5, 2><<<576, 256, 0, stream>>>(corep, dpad, out);
  kpn_sec<5, 9, 3><<<576, 256, 0, stream>>>(corep, dpad, out);
  kpn_sec<6, 14, 4><<<576, 256, 0, stream>>>(corep, dpad, out);
  kpn_sec<7, 20, 5><<<576, 256, 0, stream>>>(corep, dpad, out);
  kpn_sec<8, 27, 6><<<576, 256, 0, stream>>>(corep, dpad, out);
}

// Round 4
// 388.647 us; speedup vs baseline: 2.0216x; 1.3858x over previous
//
#include <hip/hip_runtime.h>
#include <hip/hip_bf16.h>

typedef __attribute__((ext_vector_type(4))) float f32x4;
typedef __attribute__((ext_vector_type(8))) short bf16x8;
typedef __attribute__((ext_vector_type(4))) unsigned short u16x4;
typedef unsigned short u16;

constexpr int HH = 384, WW = 384;
constexpr int AWP = 386;               // padded activation width (+1 halo each side)
constexpr int ASTR = AWP * 64;         // elements per padded activation row
constexpr int NPIX = HH * WW;          // 147456
constexpr int NPIX3 = NPIX * 3;        // 442368 (one output tensor)
constexpr int DP = 398, DPLANE = DP * DP;  // data padded by 7 each side
constexpr size_t ACT_BYTES = (size_t)AWP * AWP * 64 * 2;  // 19,071,488
constexpr int WSW = 72 * 512;          // swizzled weights per conv: 72 iters * 64 lanes * 8

__device__ __forceinline__ u16 f2bf(float f) {
  union { __hip_bfloat16 h; u16 u; } v; v.h = __float2bfloat16(f); return v.u;
}
__device__ __forceinline__ float bf2f(u16 u) {
  union { float f; unsigned int i; } v; v.i = ((unsigned int)u) << 16; return v.f;
}

// ---------------- weight/bias repack ----------------
// wpack[c][iter][lane][j] bf16 pre-swizzled to MFMA A-fragment order:
//   iter = (tap*2 + ich)*4 + m;  oc = m*16 + (lane&15);  ic = ich*32 + (lane>>4)*8 + j
// bpack[c][oc] f32 (oc>=35 zeroed for conv 6); wfr[ictap][oc] f32 for first conv
__global__ void repack_kern(const float* __restrict__ w1, const float* __restrict__ w2,
                            const float* __restrict__ wo, const float* __restrict__ b1,
                            const float* __restrict__ b2, const float* __restrict__ bo,
                            const float* __restrict__ wf,
                            u16* __restrict__ wpack, float* __restrict__ bpack,
                            float* __restrict__ wfr)
{
  const int idx = blockIdx.x * 256 + threadIdx.x;
  constexpr int NW = 7 * WSW;
  if (idx < NW) {
    const int c = idx / WSW;
    const int r = idx % WSW;
    const int iter = r / 512;
    const int lane = (r % 512) / 8;
    const int j = r % 8;
    const int tap = iter >> 3;
    const int ich = (iter >> 2) & 1;
    const int m = iter & 3;
    const int oc = m * 16 + (lane & 15);
    const int ic = ich * 32 + (lane >> 4) * 8 + j;
    float v;
    if (c < 6) {
      const float* s = (c & 1) ? w2 : w1;
      v = s[(((c >> 1) * 64 + oc) * 64 + ic) * 9 + tap];
    } else {
      v = (oc < 35) ? wo[(oc * 64 + ic) * 9 + tap] : 0.f;
    }
    wpack[idx] = f2bf(v);
  } else if (idx < NW + 448) {
    const int t = idx - NW;
    const int c = t / 64, oc = t % 64;
    float v;
    if (c < 6) v = ((c & 1) ? b2 : b1)[(c >> 1) * 64 + oc];
    else v = (oc < 35) ? bo[oc] : 0.f;
    bpack[t] = v;
  } else if (idx < NW + 448 + 3456) {
    const int t = idx - NW - 448;
    const int ictap = t / 64, oc = t % 64;
    wfr[t] = wf[oc * 54 + ictap];
  }
}

// ---------------- pad-copy data (fp32, halo 7) ----------------
__global__ void padcopy_kern(const float* __restrict__ data, float* __restrict__ dpad)
{
  const int idx = blockIdx.x * 256 + threadIdx.x;  // exactly 442368 threads
  const int c = idx / NPIX, r = idx % NPIX;
  const int y = r / WW, x = r % WW;
  dpad[c * DPLANE + (y + 7) * DP + (x + 7)] = data[idx];
}

// ---------------- first conv: 6 -> 64, fp32 direct, writes NHWC bf16 ----------------
// block = (64 px, 4 oc-groups); each thread computes 16 oc for one pixel.
__global__ __launch_bounds__(256)
void conv1_kern(const float* __restrict__ din, const float* __restrict__ wr,
                const float* __restrict__ bias, u16* __restrict__ outb)
{
  const int px = blockIdx.x * 64 + threadIdx.x;   // 2304*64 = NPIX exactly
  const int ocg = threadIdx.y;                    // 0..3
  const int y = px / WW, x = px % WW;
  f32x4 acc[4];
  #pragma unroll
  for (int j = 0; j < 4; ++j) acc[j] = *(const f32x4*)(bias + ocg * 16 + j * 4);
  for (int ic = 0; ic < 6; ++ic) {
    #pragma unroll
    for (int kr = 0; kr < 3; ++kr) {
      const int yy = y + kr - 1;
      #pragma unroll
      for (int kc = 0; kc < 3; ++kc) {
        const int xx = x + kc - 1;
        float v = 0.f;
        if (yy >= 0 && yy < HH && xx >= 0 && xx < WW)
          v = din[ic * NPIX + yy * WW + xx];
        const float* w = wr + ((ic * 3 + kr) * 3 + kc) * 64 + ocg * 16;
        #pragma unroll
        for (int j = 0; j < 4; ++j) {
          const f32x4 wv = *(const f32x4*)(w + j * 4);
          acc[j] += wv * v;
        }
      }
    }
  }
  u16* ob = outb + ((size_t)(y + 1) * AWP + (x + 1)) * 64 + ocg * 16;
  #pragma unroll
  for (int j = 0; j < 4; ++j) {
    u16x4 s;
    #pragma unroll
    for (int t = 0; t < 4; ++t) s[t] = f2bf(acc[j][t]);
    *(u16x4*)(ob + j * 4) = s;
  }
}

// ---------------- MFMA implicit-GEMM 3x3 conv, 64->64 (or ->35 planar f32) ----------------
// MODE 0: +bias, relu, store bf16 NHWC padded
// MODE 1: +bias, +residual (in-place on outb), store bf16 NHWC padded
// MODE 2: +bias, store f32 planar [oc][pix] for oc < 35
template<int MODE>
__global__ __launch_bounds__(128)
void conv_mfma(const u16* __restrict__ in, const u16* __restrict__ wp,
               const float* __restrict__ bias, u16* __restrict__ outb,
               float* __restrict__ outf)
{
  const int lane = threadIdx.x & 63;
  const int wv = threadIdx.x >> 6;
  const int l15 = lane & 15, g8 = lane >> 4;
  const int y = blockIdx.y;
  const int x0 = blockIdx.x * 128 + wv * 64;

  f32x4 acc[4][4];
  #pragma unroll
  for (int m = 0; m < 4; ++m)
    #pragma unroll
    for (int n = 0; n < 4; ++n)
      acc[m][n] = f32x4{0.f, 0.f, 0.f, 0.f};

  #pragma unroll
  for (int tap = 0; tap < 9; ++tap) {
    const int kr = tap / 3, kc = tap % 3;
    const u16* inr = in + (size_t)(y + kr) * ASTR + (size_t)(x0 + kc) * 64;
    #pragma unroll
    for (int ich = 0; ich < 2; ++ich) {
      const u16* wpi = wp + ((tap * 2 + ich) * 4) * 512 + lane * 8;  // coalesced A-frags
      bf16x8 a[4], b[4];
      #pragma unroll
      for (int m = 0; m < 4; ++m)
        a[m] = *(const bf16x8*)(wpi + m * 512);
      #pragma unroll
      for (int n = 0; n < 4; ++n)
        b[n] = *(const bf16x8*)(inr + (size_t)(n * 16 + l15) * 64 + ich * 32 + g8 * 8);
      #pragma unroll
      for (int m = 0; m < 4; ++m)
        #pragma unroll
        for (int n = 0; n < 4; ++n)
          acc[m][n] = __builtin_amdgcn_mfma_f32_16x16x32_bf16(a[m], b[n], acc[m][n], 0, 0, 0);
    }
  }

  const int oc_lo = g8 * 4;
  #pragma unroll
  for (int m = 0; m < 4; ++m) {
    const int oc0 = m * 16 + oc_lo;                  // D row = (lane>>4)*4 + reg
    const f32x4 bv = *(const f32x4*)(bias + oc0);
    #pragma unroll
    for (int n = 0; n < 4; ++n) {
      const int px = x0 + n * 16 + l15;              // D col = lane&15
      f32x4 v = acc[m][n] + bv;
      if constexpr (MODE == 0) {
        #pragma unroll
        for (int j = 0; j < 4; ++j) v[j] = v[j] > 0.f ? v[j] : 0.f;
      }
      if constexpr (MODE == 1) {
        const u16x4 r = *(const u16x4*)(outb + ((size_t)(y + 1) * AWP + (px + 1)) * 64 + oc0);
        #pragma unroll
        for (int j = 0; j < 4; ++j) v[j] += bf2f(r[j]);
      }
      if constexpr (MODE <= 1) {
        u16x4 s;
        #pragma unroll
        for (int j = 0; j < 4; ++j) s[j] = f2bf(v[j]);
        *(u16x4*)(outb + ((size_t)(y + 1) * AWP + (px + 1)) * 64 + oc0) = s;
      } else {
        // planar f32 store, only real channels
        #pragma unroll
        for (int j = 0; j < 4; ++j) {
          const int oc = oc0 + j;
          if (oc < 35) outf[(size_t)oc * NPIX + (size_t)y * WW + px] = v[j];
        }
      }
    }
  }
}

// ---------------- KPN apply: per-section body, single kernel ----------------
template<int WIDE, int OFF, int SEC>
__device__ __forceinline__ void kpn_body(const float* __restrict__ corep,
                                         const float* __restrict__ dpad,
                                         float* __restrict__ out)
{
  const int px = blockIdx.x * 256 + threadIdx.x;      // 576*256 = NPIX exactly
  const int y = px / WW, x = px % WW;
  const float* base = dpad + (size_t)(y + 7) * DP + (x + 7);

  float ck[WIDE];
  #pragma unroll
  for (int i = 0; i < WIDE; ++i) ck[i] = fabsf(corep[(size_t)(OFF + i) * NPIX + px]);

  float s = 0.f, p0 = 0.f, p1 = 0.f, p2 = 0.f;
  #pragma unroll
  for (int a = 0; a < WIDE; ++a) {
    #pragma unroll
    for (int b = 0; b < WIDE; ++b) {
      const int d2 = a * a + b * b;
      int li = 0;                                     // integer floor sqrt, folds
      while ((li + 1) * (li + 1) <= d2) ++li;
      const bool exact = (li * li == d2);
      const int hraw = li + (exact ? 0 : 1);
      const int lidx = li < WIDE - 1 ? li : WIDE - 1;
      const int hidx = hraw < WIDE - 1 ? hraw : WIDE - 1;
      const bool msk = d2 <= (WIDE - 1) * (WIDE - 1);
      float e;
      if (msk) {
        const float d = sqrtf((float)d2);
        const float wlo = exact ? 1.f : ((float)hraw - d);
        const float whi = exact ? 0.f : (d - (float)li);
        const float q = wlo * ck[lidx] + whi * ck[hidx];
        e = __expf(q);
      } else {
        e = 1.f;                                      // masked: logit 0, still in softmax
      }
      const float mult = (float)(((a > 0) ? 2 : 1) * ((b > 0) ? 2 : 1));
      s += mult * e;
      #pragma unroll
      for (int c = 0; c < 3; ++c) {
        const float* bc = base + c * DPLANE;
        float g = bc[a * DP + b];
        if (b > 0) g += bc[a * DP - b];
        if (a > 0) g += bc[-a * DP + b];
        if (a > 0 && b > 0) g += bc[-a * DP - b];
        if (c == 0) p0 += e * g; else if (c == 1) p1 += e * g; else p2 += e * g;
      }
    }
  }
  const float inv = 1.f / s;
  float* o = out + (size_t)(SEC + 1) * NPIX3 + px;
  o[0] = p0 * inv; o[NPIX] = p1 * inv; o[2 * NPIX] = p2 * inv;
}

__global__ __launch_bounds__(256, 4)
void kpn_all(const float* __restrict__ corep, const float* __restrict__ dpad,
             float* __restrict__ out)
{
  switch (blockIdx.y) {
    case 0: kpn_body<2, 0, 0>(corep, dpad, out); break;
    case 1: kpn_body<3, 2, 1>(corep, dpad, out); break;
    case 2: kpn_body<4, 5, 2>(corep, dpad, out); break;
    case 3: kpn_body<5, 9, 3>(corep, dpad, out); break;
    case 4: kpn_body<6, 14, 4>(corep, dpad, out); break;
    case 5: kpn_body<7, 20, 5>(corep, dpad, out); break;
    default: kpn_body<8, 27, 6>(corep, dpad, out); break;
  }
}

// ---------------- launch ----------------
extern "C" void kernel_launch(void* const* d_in, const int* in_sizes, int n_in,
                              void* d_out, int out_size, void* d_ws, size_t ws_size,
                              hipStream_t stream)
{
  const float* d_est   = (const float*)d_in[0];
  const float* data    = (const float*)d_in[1];
  const float* w_first = (const float*)d_in[2];
  const float* b_first = (const float*)d_in[3];
  const float* w_blk1  = (const float*)d_in[4];
  const float* b_blk1  = (const float*)d_in[5];
  const float* w_blk2  = (const float*)d_in[6];
  const float* b_blk2  = (const float*)d_in[7];
  const float* w_out   = (const float*)d_in[8];
  const float* b_out   = (const float*)d_in[9];

  char* ws = (char*)d_ws;
  const size_t OFF_A1    = ACT_BYTES;
  const size_t OFF_CORE  = 2 * ACT_BYTES;
  const size_t OFF_DPAD  = OFF_CORE + (size_t)35 * NPIX * 4;
  const size_t OFF_WPACK = OFF_DPAD + (size_t)3 * DPLANE * 4;
  const size_t OFF_BPACK = OFF_WPACK + (size_t)7 * WSW * 2;
  const size_t OFF_WFR   = OFF_BPACK + 448 * 4;

  u16*   A0    = (u16*)(ws);
  u16*   A1    = (u16*)(ws + OFF_A1);
  float* corep = (float*)(ws + OFF_CORE);
  float* dpad  = (float*)(ws + OFF_DPAD);
  u16*   wpack = (u16*)(ws + OFF_WPACK);
  float* bpack = (float*)(ws + OFF_BPACK);
  float* wfr   = (float*)(ws + OFF_WFR);

  hipMemsetAsync(A0, 0, ACT_BYTES, stream);
  hipMemsetAsync(A1, 0, ACT_BYTES, stream);
  hipMemsetAsync(dpad, 0, (size_t)3 * DPLANE * 4, stream);
  // output 0 is an exact copy of `data`
  hipMemcpyAsync(d_out, data, (size_t)NPIX3 * 4, hipMemcpyDeviceToDevice, stream);

  repack_kern<<<1024, 256, 0, stream>>>(w_blk1, w_blk2, w_out, b_blk1, b_blk2, b_out,
                                        w_first, wpack, bpack, wfr);
  padcopy_kern<<<1728, 256, 0, stream>>>(data, dpad);
  conv1_kern<<<2304, dim3(64, 4), 0, stream>>>(d_est, wfr, b_first, A0);

  dim3 cg(3, 384);
  for (int i = 0; i < 3; ++i) {
    conv_mfma<0><<<cg, 128, 0, stream>>>(A0, wpack + (size_t)(2 * i) * WSW,
                                         bpack + (2 * i) * 64, A1, nullptr);
    conv_mfma<1><<<cg, 128, 0, stream>>>(A1, wpack + (size_t)(2 * i + 1) * WSW,
                                         bpack + (2 * i + 1) * 64, A0, nullptr);
  }
  conv_mfma<2><<<cg, 128, 0, stream>>>(A0, wpack + (size_t)6 * WSW,
                                       bpack + 6 * 64, nullptr, corep);

  kpn_all<<<dim3(576, 7), 256, 0, stream>>>(corep, dpad, (float*)d_out);
}